// Round 9
// baseline (563.952 us; speedup 1.0000x reference)
//
#include <hip/hip_runtime.h>
#include <math.h>

#define SEQ 1024
#define BATCH 4
#define DMODEL 512
#define NHEAD 8
#define DK 64
#define DFF 2048
#define U_TOP 34
#define ROWS (BATCH * SEQ)

typedef unsigned short ushort_t;
typedef __attribute__((ext_vector_type(8))) short short8;
typedef __attribute__((ext_vector_type(4))) float float4v;

__device__ inline ushort_t f2bf(float f) {
  unsigned u = __float_as_uint(f);
  unsigned r = u + 0x7fffu + ((u >> 16) & 1u);
  return (ushort_t)(r >> 16);
}
__device__ inline float bf2f(ushort_t u) {
  return __uint_as_float((unsigned)u << 16);
}
// ordered-uint key -> float (rare >64-candidate fallback only)
__device__ inline float keyinv(unsigned cand) {
  unsigned fb = (cand & 0x80000000u) ? (cand ^ 0x80000000u) : ~cand;
  return __uint_as_float(fb);
}

union H16 { _Float16 h; unsigned short u; };
__device__ inline unsigned short h2u(float f) {
  H16 t; t.h = (_Float16)f; return t.u;
}
__device__ inline float u2h(unsigned short u) {
  H16 t; t.u = u; return (float)t.h;
}
__device__ inline int mbcnt64(unsigned long long m) {
  int lo = __builtin_amdgcn_mbcnt_lo((unsigned)m, 0);
  return __builtin_amdgcn_mbcnt_hi((unsigned)(m >> 32), lo);
}

__device__ inline void glds16(const void* g, void* l) {
  __builtin_amdgcn_global_load_lds(
      (const __attribute__((address_space(1))) unsigned int*)g,
      (__attribute__((address_space(3))) unsigned int*)l, 16, 0, 0);
}

// Descending bitonic sort of TWO independent values/lane (interleaved chains
// hide ds_swizzle latency). After: lane i holds (i+1)-th largest.
__device__ inline void bitonic64x2(float& a, float& b, int lane) {
#pragma unroll
  for (int k = 2; k <= 64; k <<= 1) {
#pragma unroll
    for (int j = k >> 1; j > 0; j >>= 1) {
      float pa = __shfl_xor(a, j);
      float pb = __shfl_xor(b, j);
      bool keepMin = (((lane & k) != 0) == ((lane & j) == 0));
      a = keepMin ? fminf(a, pa) : fmaxf(a, pa);
      b = keepMin ? fminf(b, pb) : fmaxf(b, pb);
    }
  }
}

// ---------------------------------------------------------------------------
// bf16 MFMA GEMM, m97 structure: 128x128 tile, BK=32, 256 thr = 2x2 waves.
// SPLIT=1 (QKV): Bt has 1536 rows (Wq|Wk|Wv); z=bn>>9 routes output/bias.
// ---------------------------------------------------------------------------
template <int RELU, int SPLIT>
__global__ __launch_bounds__(256) void gemm128(
    const ushort_t* __restrict__ A, const short* __restrict__ Bt,
    const float* __restrict__ b0, const float* __restrict__ b1,
    const float* __restrict__ b2, ushort_t* __restrict__ Cout,
    int K, int N, int zCstride) {
  __shared__ short As[128 * 32];
  __shared__ short Bs[128 * 32];

  const int tid = threadIdx.x;
  const int lane = tid & 63, w = tid >> 6;
  const int wm = w >> 1, wn = w & 1;
  const int quad = lane >> 4, r16 = lane & 15;
  const int bm = blockIdx.y * 128, bn = blockIdx.x * 128;

  const int srow = lane >> 2, skseg = lane & 3;
  const ushort_t* Ag0 = A + (size_t)(bm + w * 16 + srow) * K + skseg * 8;
  const ushort_t* Ag1 = Ag0 + (size_t)64 * K;
  const short* Bg0 = Bt + (size_t)(bn + w * 16 + srow) * K + skseg * 8;
  const short* Bg1 = Bg0 + (size_t)64 * K;
  short* lA0 = As + (w * 16) * 32;
  short* lA1 = As + (64 + w * 16) * 32;
  short* lB0 = Bs + (w * 16) * 32;
  short* lB1 = Bs + (64 + w * 16) * 32;

  float4v acc[4][4];
#pragma unroll
  for (int m = 0; m < 4; ++m)
#pragma unroll
    for (int n = 0; n < 4; ++n) acc[m][n] = (float4v){0.f, 0.f, 0.f, 0.f};

  for (int k0 = 0; k0 < K; k0 += 32) {
    __syncthreads();
    glds16(Ag0 + k0, lA0);
    glds16(Ag1 + k0, lA1);
    glds16(Bg0 + k0, lB0);
    glds16(Bg1 + k0, lB1);
    __syncthreads();

    short8 af[4], bfr[4];
#pragma unroll
    for (int m = 0; m < 4; ++m)
      af[m] = *(const short8*)&As[(wm * 64 + m * 16 + r16) * 32 + quad * 8];
#pragma unroll
    for (int n = 0; n < 4; ++n)
      bfr[n] = *(const short8*)&Bs[(wn * 64 + n * 16 + r16) * 32 + quad * 8];
#pragma unroll
    for (int m = 0; m < 4; ++m)
#pragma unroll
      for (int n = 0; n < 4; ++n)
        acc[m][n] = __builtin_amdgcn_mfma_f32_16x16x32_bf16(af[m], bfr[n],
                                                            acc[m][n], 0, 0, 0);
  }

  const int z = SPLIT ? (bn >> 9) : 0;
  const float* bias = (z == 0) ? b0 : (z == 1 ? b1 : b2);
  const int cbase = SPLIT ? (bn & 511) : bn;
  const int strideN = SPLIT ? 512 : N;
  ushort_t* C = Cout + (SPLIT ? (size_t)z * zCstride : (size_t)0);

  float bias_n[4];
#pragma unroll
  for (int n = 0; n < 4; ++n)
    bias_n[n] = bias[cbase + wn * 64 + n * 16 + r16];

#pragma unroll
  for (int m = 0; m < 4; ++m) {
#pragma unroll
    for (int n = 0; n < 4; ++n) {
      int col = cbase + wn * 64 + n * 16 + r16;
#pragma unroll
      for (int reg = 0; reg < 4; ++reg) {
        int row = bm + wm * 64 + m * 16 + quad * 4 + reg;
        float v = acc[m][n][reg] + bias_n[n];
        if (RELU) v = fmaxf(v, 0.f);
        C[(size_t)row * strideN + col] = f2bf(v);
      }
    }
  }
}

// ---------------------------------------------------------------------------
// bf16 MFMA GEMM, tile 64x64, BK=32, 256 threads = 2x2 waves, 12 KB LDS.
// EPI 0: none. EPI 2: v = v*sqrt(512) + positional encoding (embed).
// ---------------------------------------------------------------------------
template <int RELU, int OUTBF16, int EPI, int ADDC>
__global__ __launch_bounds__(256) void gemm64(
    const ushort_t* __restrict__ A, const short* __restrict__ Bt,
    const float* __restrict__ bias, void* __restrict__ Cout,
    const ushort_t* __restrict__ Cadd, int K, int N) {
  __shared__ short As[64 * 32];
  __shared__ short Bs[64 * 32];

  const int tid = threadIdx.x;
  const int lane = tid & 63, w = tid >> 6;
  const int wm = w >> 1, wn = w & 1;
  const int quad = lane >> 4, r16 = lane & 15;
  const int bm = blockIdx.y * 64, bn = blockIdx.x * 64;

  const int srow = tid >> 2, skseg = tid & 3;
  const ushort_t* Ag = A + (size_t)(bm + srow) * K + skseg * 8;
  const short* Bg = Bt + (size_t)(bn + srow) * K + skseg * 8;
  short* lA = As + w * 512;
  short* lB = Bs + w * 512;

  float4v acc[2][2];
#pragma unroll
  for (int m = 0; m < 2; ++m)
#pragma unroll
    for (int n = 0; n < 2; ++n) acc[m][n] = (float4v){0.f, 0.f, 0.f, 0.f};

  for (int k0 = 0; k0 < K; k0 += 32) {
    __syncthreads();
    glds16(Ag + k0, lA);
    glds16(Bg + k0, lB);
    __syncthreads();

    short8 af[2], bfr[2];
#pragma unroll
    for (int m = 0; m < 2; ++m)
      af[m] = *(const short8*)&As[(wm * 32 + m * 16 + r16) * 32 + quad * 8];
#pragma unroll
    for (int n = 0; n < 2; ++n)
      bfr[n] = *(const short8*)&Bs[(wn * 32 + n * 16 + r16) * 32 + quad * 8];
#pragma unroll
    for (int m = 0; m < 2; ++m)
#pragma unroll
      for (int n = 0; n < 2; ++n)
        acc[m][n] = __builtin_amdgcn_mfma_f32_16x16x32_bf16(af[m], bfr[n],
                                                            acc[m][n], 0, 0, 0);
  }

  const float pe_c = (float)(-9.210340371976184 / 512.0);
  const float sqrtd = 22.62741699796952f;

  float bias_n[2];
#pragma unroll
  for (int n = 0; n < 2; ++n) bias_n[n] = bias[bn + wn * 32 + n * 16 + r16];

#pragma unroll
  for (int m = 0; m < 2; ++m) {
#pragma unroll
    for (int n = 0; n < 2; ++n) {
      int col = bn + wn * 32 + n * 16 + r16;
#pragma unroll
      for (int reg = 0; reg < 4; ++reg) {
        int row = bm + wm * 32 + m * 16 + quad * 4 + reg;
        float v = acc[m][n][reg] + bias_n[n];
        if (RELU) v = fmaxf(v, 0.f);
        if (EPI == 2) {
          int pos = row & (SEQ - 1);
          float e = __expf((float)(col & ~1) * pe_c);
          float arg = (float)pos * e;
          v = v * sqrtd + ((col & 1) ? __cosf(arg) : __sinf(arg));
        }
        if (ADDC) v += bf2f(Cadd[(size_t)row * N + col]);
        if (OUTBF16) {
          ((ushort_t*)Cout)[(size_t)row * N + col] = f2bf(v);
        } else {
          ((float*)Cout)[(size_t)row * N + col] = v;
        }
      }
    }
  }
}

// ---------------------------------------------------------------------------
// All weights (3 layers + emb + dec): W[K][N] f32 -> Wt[N][K] bf16, 1 launch.
// ---------------------------------------------------------------------------
__global__ __launch_bounds__(256) void convert_all(
    const float* __restrict__ Wq, const float* __restrict__ Wk,
    const float* __restrict__ Wv, const float* __restrict__ Wo,
    const float* __restrict__ W1, const float* __restrict__ W2,
    const float* __restrict__ W_emb, const float* __restrict__ W_dec,
    short* __restrict__ wt) {
  __shared__ float t[32][33];
  int id = blockIdx.x;
  const float* src;
  short* dst;
  int K, N, tk, tn;
  if (id < 9216) {
    int lay = id / 3072, r = id % 3072;
    short* wl = wt + (size_t)lay * 3145728;
    const size_t wsz = 512 * 512;
    if (r < 1024) {
      int wi = r >> 8, tile = r & 255;
      const float* base = (wi == 0) ? Wq : (wi == 1) ? Wk : (wi == 2) ? Wv : Wo;
      src = base + lay * wsz;
      dst = wl + wi * 262144;
      K = 512; N = 512; tk = tile >> 4; tn = tile & 15;
    } else if (r < 2048) {
      int tile = r - 1024;
      src = W1 + (size_t)lay * 512 * 2048;
      dst = wl + 1048576;
      K = 512; N = 2048; tk = tile >> 6; tn = tile & 63;
    } else {
      int tile = r - 2048;
      src = W2 + (size_t)lay * 2048 * 512;
      dst = wl + 2097152;
      K = 2048; N = 512; tk = tile >> 4; tn = tile & 15;
    }
  } else {
    int r = id - 9216;
    if (r < 64) {
      src = W_emb; dst = wt + 9437184; K = 128; N = 512; tk = r >> 4; tn = r & 15;
    } else {
      r -= 64;
      src = W_dec; dst = wt + 9502720; K = 512; N = 64; tk = r >> 1; tn = r & 1;
    }
  }
  const int k0 = tk * 32, n0 = tn * 32;
  const int tx = threadIdx.x, ty = threadIdx.y;
#pragma unroll
  for (int i = 0; i < 4; ++i) {
    int r = ty + i * 8;
    t[r][tx] = src[(size_t)(k0 + r) * N + n0 + tx];
  }
  __syncthreads();
#pragma unroll
  for (int i = 0; i < 4; ++i) {
    int r = ty + i * 8;
    dst[(size_t)(n0 + r) * K + k0 + tx] = (short)f2bf(t[tx][r]);
  }
}

__global__ __launch_bounds__(256) void f32_to_bf16_kernel(
    const float* __restrict__ src, ushort_t* __restrict__ dst) {
  int i = blockIdx.x * blockDim.x + threadIdx.x;
  float4 v = ((const float4*)src)[i];
  ushort4 o;
  o.x = f2bf(v.x); o.y = f2bf(v.y); o.z = f2bf(v.z); o.w = f2bf(v.w);
  ((ushort4*)dst)[i] = o;
}

// ---------------------------------------------------------------------------
// LayerNorm on pre-summed bf16 input: hb[row] = LN(t1b[row]) * g + b.
// ---------------------------------------------------------------------------
__global__ __launch_bounds__(256) void ln_kernel(
    const ushort_t* __restrict__ t1b, const float* __restrict__ g,
    const float* __restrict__ bb, ushort_t* __restrict__ hb) {
  const int row = blockIdx.x * 4 + (threadIdx.x >> 6);
  const int lane = threadIdx.x & 63;
  const size_t base = (size_t)row * DMODEL + lane * 8;
  uint4 raw = *(const uint4*)(t1b + base);
  unsigned rr[4] = {raw.x, raw.y, raw.z, raw.w};
  float v[8];
#pragma unroll
  for (int k = 0; k < 4; ++k) {
    v[2 * k] = bf2f((ushort_t)(rr[k] & 0xffff));
    v[2 * k + 1] = bf2f((ushort_t)(rr[k] >> 16));
  }
  float sum = 0.f, sq = 0.f;
#pragma unroll
  for (int k = 0; k < 8; ++k) { sum += v[k]; sq += v[k] * v[k]; }
#pragma unroll
  for (int off = 32; off; off >>= 1) {
    sum += __shfl_xor(sum, off);
    sq += __shfl_xor(sq, off);
  }
  float mean = sum * (1.f / 512.f);
  float var = fmaxf(sq * (1.f / 512.f) - mean * mean, 0.f);
  float rstd = 1.f / sqrtf(var + 1e-5f);
  float4 g0 = *(const float4*)(g + lane * 8);
  float4 g1 = *(const float4*)(g + lane * 8 + 4);
  float4 c0 = *(const float4*)(bb + lane * 8);
  float4 c1 = *(const float4*)(bb + lane * 8 + 4);
  float gg[8] = {g0.x, g0.y, g0.z, g0.w, g1.x, g1.y, g1.z, g1.w};
  float cc[8] = {c0.x, c0.y, c0.z, c0.w, c1.x, c1.y, c1.z, c1.w};
  uint4 out;
  unsigned* op = (unsigned*)&out;
#pragma unroll
  for (int k = 0; k < 4; ++k) {
    float y0 = (v[2 * k] - mean) * rstd * gg[2 * k] + cc[2 * k];
    float y1 = (v[2 * k + 1] - mean) * rstd * gg[2 * k + 1] + cc[2 * k + 1];
    op[k] = (unsigned)f2bf(y0) | ((unsigned)f2bf(y1) << 16);
  }
  *(uint4*)(hb + base) = out;
}

// ---------------------------------------------------------------------------
// ProbSparse attention v8: 512-thread blocks (8 waves), QT=16 queries.
// Phase 1: wave w computes S[16q][128k] (keys [128w,128w+128)) via 16 MFMAs,
//   stores scores as fp16 to LDS s16[16][SST] (SST=1048: quad-row writes
//   land 2-way = free; reads conflict-free).
// Phase 2: wave w owns TWO queries {w, w+8}; sorts/ballots/PV run as
//   interleaved independent chains (hides ds_swizzle latency, the R8 limiter).
//   sort1 (lane maxima, x2) -> mx, fT; compact candidates {v>=fT} into packed
//   u32 (j<<16 | fp16 exp(v-mx)); sort2 over candidate weights (exp monotone
//   in v) -> exact 34th-largest; keep/zsum/PV. mbcnt for prefix sums.
// LDS 37.6 KB -> 4 blocks/CU (32 waves) at 8-wave barrier granularity.
// ---------------------------------------------------------------------------
#define SST 1048

__global__ __launch_bounds__(512, 8) void attn_kernel(
    const ushort_t* __restrict__ Qb, const ushort_t* __restrict__ Kb,
    const ushort_t* __restrict__ Vb, ushort_t* __restrict__ Ob) {
  __shared__ _Float16 s16[16 * SST];
  __shared__ unsigned plist[16][64];

  const int tid = threadIdx.x;
  const int q0 = blockIdx.x * 16;
  const int h = blockIdx.y;
  const int b = blockIdx.z;
  const int w = tid >> 6;
  const int lane = tid & 63;
  const int quad = lane >> 4, r16 = lane & 15;

  // ---- Phase 1: MFMA scores (16 queries x 128 keys per wave) ----
  {
    const int j0 = w * 128;
    const ushort_t* qrow =
        Qb + (size_t)(b * SEQ + q0 + r16) * DMODEL + h * DK + quad * 8;
    short8 aq0 = *(const short8*)qrow;
    short8 aq1 = *(const short8*)(qrow + 32);

#pragma unroll
    for (int nt = 0; nt < 8; ++nt) {
      const ushort_t* krow =
          Kb + (size_t)(b * SEQ + j0 + nt * 16 + r16) * DMODEL + h * DK +
          quad * 8;
      short8 bk0 = *(const short8*)krow;
      short8 bk1 = *(const short8*)(krow + 32);
      float4v a = (float4v){0.f, 0.f, 0.f, 0.f};
      a = __builtin_amdgcn_mfma_f32_16x16x32_bf16(aq0, bk0, a, 0, 0, 0);
      a = __builtin_amdgcn_mfma_f32_16x16x32_bf16(aq1, bk1, a, 0, 0, 0);
#pragma unroll
      for (int reg = 0; reg < 4; ++reg)
        s16[(quad * 4 + reg) * SST + j0 + nt * 16 + r16] =
            (_Float16)(a[reg] * 0.125f);
    }
  }
  __syncthreads();

  // ---- Phase 2: two queries per wave, interleaved chains ----
  {
    const int qa = w, qb2 = w + 8;
    const _Float16* sa = &s16[qa * SST];
    const _Float16* sb = &s16[qb2 * SST];

    // lane maxima (both queries)
    float la = -1e30f, lb = -1e30f;
#pragma unroll
    for (int i = 0; i < 16; ++i) {
      la = fmaxf(la, (float)sa[lane + 64 * i]);
      lb = fmaxf(lb, (float)sb[lane + 64 * i]);
    }

    float sva = la, svb = lb;
    bitonic64x2(sva, svb, lane);
    const float mxa = __shfl(sva, 0), mxb = __shfl(svb, 0);
    const float fTa = __shfl(sva, 33), fTb = __shfl(svb, 33);

    // optimistic compaction at fT (counts + packed (j, fp16 weight) writes)
    int ca = 0, cb = 0;
#pragma unroll
    for (int i = 0; i < 16; ++i) {
      float va = (float)sa[lane + 64 * i];
      float vb = (float)sb[lane + 64 * i];
      bool ka = va >= fTa, kb = vb >= fTb;
      unsigned long long ma = __ballot(ka);
      unsigned long long mb = __ballot(kb);
      if (ka) {
        int p = ca + mbcnt64(ma);
        if (p < 64)
          plist[qa][p] = ((unsigned)(lane + 64 * i) << 16) |
                         h2u(__expf(va - mxa));
      }
      if (kb) {
        int p = cb + mbcnt64(mb);
        if (p < 64)
          plist[qb2][p] = ((unsigned)(lane + 64 * i) << 16) |
                          h2u(__expf(vb - mxb));
      }
      ca += (int)__popcll(ma);
      cb += (int)__popcll(mb);
    }

    // rare fallback: >64 candidates -> uint bisection to tighter threshold
    if (__builtin_expect(ca > 64, 0)) {
      unsigned ans = 0u;
      int cge = ca;
      bool ex = false;
      for (int bit = 31; bit >= 0 && cge > 64 && !ex; --bit) {
        unsigned cand = ans | (1u << bit);
        float fc = keyinv(cand);
        int c = 0;
#pragma unroll
        for (int i = 0; i < 16; ++i)
          c += (int)__popcll(__ballot((float)sa[lane + 64 * i] >= fc));
        if (c >= U_TOP) { ans = cand; cge = c; ex = (c == U_TOP); }
      }
      float fa2 = keyinv(ans);
      int cc = 0;
#pragma unroll
      for (int i = 0; i < 16; ++i) {
        float va = (float)sa[lane + 64 * i];
        bool ka = va >= fa2;
        unsigned long long ma = __ballot(ka);
        if (ka) {
          int p = cc + mbcnt64(ma);
          if (p < 64)
            plist[qa][p] = ((unsigned)(lane + 64 * i) << 16) |
                           h2u(__expf(va - mxa));
        }
        cc += (int)__popcll(ma);
      }
      ca = cc;
    }
    if (__builtin_expect(cb > 64, 0)) {
      unsigned ans = 0u;
      int cge = cb;
      bool ex = false;
      for (int bit = 31; bit >= 0 && cge > 64 && !ex; --bit) {
        unsigned cand = ans | (1u << bit);
        float fc = keyinv(cand);
        int c = 0;
#pragma unroll
        for (int i = 0; i < 16; ++i)
          c += (int)__popcll(__ballot((float)sb[lane + 64 * i] >= fc));
        if (c >= U_TOP) { ans = cand; cge = c; ex = (c == U_TOP); }
      }
      float fb2 = keyinv(ans);
      int cc = 0;
#pragma unroll
      for (int i = 0; i < 16; ++i) {
        float vb = (float)sb[lane + 64 * i];
        bool kb = vb >= fb2;
        unsigned long long mb = __ballot(kb);
        if (kb) {
          int p = cc + mbcnt64(mb);
          if (p < 64)
            plist[qb2][p] = ((unsigned)(lane + 64 * i) << 16) |
                            h2u(__expf(vb - mxb));
        }
        cc += (int)__popcll(mb);
      }
      cb = cc;
    }
    ca = ca > 64 ? 64 : ca;
    cb = cb > 64 ? 64 : cb;

    // one candidate per lane (packed); weight 0 sentinel for empty slots
    unsigned pua = (lane < ca) ? plist[qa][lane] : 0u;
    unsigned pub = (lane < cb) ? plist[qb2][lane] : 0u;
    float ea = u2h((unsigned short)(pua & 0xffffu));
    float eb = u2h((unsigned short)(pub & 0xffffu));

    // sort2 over candidate weights (exp is monotone in score)
    float s2a = ea, s2b = eb;
    bitonic64x2(s2a, s2b, lane);
    const float tha = __shfl(s2a, 33), thb = __shfl(s2b, 33);

    // keep set + zsum + recompaction (reads of plist done above)
    bool keepa = ea >= tha, keepb = eb >= thb;
    unsigned long long kma = __ballot(keepa);
    unsigned long long kmb = __ballot(keepb);
    int na = (int)__popcll(kma), nb = (int)__popcll(kmb);
    float za = keepa ? ea : 0.f, zb = keepb ? eb : 0.f;
#pragma unroll
    for (int off = 32; off; off >>= 1) {
      za += __shfl_xor(za, off);
      zb += __shfl_xor(zb, off);
    }
    int posa = mbcnt64(kma), posb = mbcnt64(kmb);
    if (keepa) plist[qa][posa] = pua;
    if (keepb) plist[qb2][posb] = pub;

    // sparse PV: two interleaved gather streams, 4 loads in flight
    const ushort_t* vbase = Vb + (size_t)b * SEQ * DMODEL + h * DK;
    float oa = 0.f, ob = 0.f;
    int nmax = na > nb ? na : nb;
    for (int i = 0; i < nmax; i += 2) {
      unsigned ua0 = (i < na) ? plist[qa][i] : 0u;
      unsigned ua1 = (i + 1 < na) ? plist[qa][i + 1] : 0u;
      unsigned ub0 = (i < nb) ? plist[qb2][i] : 0u;
      unsigned ub1 = (i + 1 < nb) ? plist[qb2][i + 1] : 0u;
      float pa0 = bf2f(vbase[(size_t)(ua0 >> 16) * DMODEL + lane]);
      float pa1 = bf2f(vbase[(size_t)(ua1 >> 16) * DMODEL + lane]);
      float pb0 = bf2f(vbase[(size_t)(ub0 >> 16) * DMODEL + lane]);
      float pb1 = bf2f(vbase[(size_t)(ub1 >> 16) * DMODEL + lane]);
      oa += u2h((unsigned short)(ua0 & 0xffffu)) * pa0 +
            u2h((unsigned short)(ua1 & 0xffffu)) * pa1;
      ob += u2h((unsigned short)(ub0 & 0xffffu)) * pb0 +
            u2h((unsigned short)(ub1 & 0xffffu)) * pb1;
    }
    oa /= za;
    ob /= zb;
    Ob[(size_t)(b * SEQ + q0 + qa) * DMODEL + h * DK + lane] = f2bf(oa);
    Ob[(size_t)(b * SEQ + q0 + qb2) * DMODEL + h * DK + lane] = f2bf(ob);
  }
}

// ---------------------------------------------------------------------------
// Orchestration.  ws layout (MiB): ffh/qkv [0,16) | ao [16,20) (xb aliases
// [16,17) pre-loop) | t1b [20,24) | hb [24,28) | wt [28, 46.2).
// ---------------------------------------------------------------------------
extern "C" void kernel_launch(void* const* d_in, const int* in_sizes, int n_in,
                              void* d_out, int out_size, void* d_ws,
                              size_t ws_size, hipStream_t stream) {
  const float* x = (const float*)d_in[0];
  const float* W_emb = (const float*)d_in[1];
  const float* b_emb = (const float*)d_in[2];
  const float* Wq = (const float*)d_in[3];
  const float* bq = (const float*)d_in[4];
  const float* Wk = (const float*)d_in[5];
  const float* bk = (const float*)d_in[6];
  const float* Wv = (const float*)d_in[7];
  const float* bv = (const float*)d_in[8];
  const float* Wo = (const float*)d_in[9];
  const float* bo = (const float*)d_in[10];
  const float* ln1_g = (const float*)d_in[11];
  const float* ln1_b = (const float*)d_in[12];
  const float* W1 = (const float*)d_in[13];
  const float* b1 = (const float*)d_in[14];
  const float* W2 = (const float*)d_in[15];
  const float* b2 = (const float*)d_in[16];
  const float* ln2_g = (const float*)d_in[17];
  const float* ln2_b = (const float*)d_in[18];
  const float* W_dec = (const float*)d_in[19];
  const float* b_dec = (const float*)d_in[20];

  char* wsb = (char*)d_ws;
  ushort_t* qkv = (ushort_t*)wsb;
  ushort_t* ffh = (ushort_t*)wsb;
  ushort_t* ao = (ushort_t*)(wsb + ((size_t)16 << 20));
  ushort_t* xb = (ushort_t*)(wsb + ((size_t)16 << 20));
  ushort_t* t1b = (ushort_t*)(wsb + ((size_t)20 << 20));
  ushort_t* hb = (ushort_t*)(wsb + ((size_t)24 << 20));
  short* wt = (short*)(wsb + ((size_t)28 << 20));
  short* wembT = wt + 9437184;
  short* wdecT = wt + 9502720;

  f32_to_bf16_kernel<<<dim3(512), 256, 0, stream>>>(x, xb);
  convert_all<<<dim3(9312), dim3(32, 8), 0, stream>>>(Wq, Wk, Wv, Wo, W1, W2,
                                                      W_emb, W_dec, wt);
  // embed: hb = bf16((xb @ W_emb + b_emb)*sqrt(512) + PE)
  gemm64<0, 1, 2, 0><<<dim3(8, 64), 256, 0, stream>>>(
      xb, wembT, b_emb, (void*)hb, nullptr, 128, 512);

  for (int i = 0; i < 3; ++i) {
    short* wtL = wt + (size_t)i * 3145728;

    // QKV: one N=1536 GEMM on the 128x128 tile, z-split epilogue
    gemm128<0, 1><<<dim3(12, 32), 256, 0, stream>>>(
        hb, wtL, bq + i * DMODEL, bk + i * DMODEL, bv + i * DMODEL, qkv, 512,
        512, 2097152);

    attn_kernel<<<dim3(SEQ / 16, NHEAD, BATCH), dim3(512), 0, stream>>>(
        qkv, qkv + 2097152, qkv + 4194304, ao);

    // t1b = ao @ Wo + bo + hb   (residual fused)
    gemm64<0, 1, 0, 1><<<dim3(8, 64), 256, 0, stream>>>(
        ao, wtL + 786432, bo + i * DMODEL, (void*)t1b, hb, 512, 512);
    ln_kernel<<<dim3(ROWS / 4), 256, 0, stream>>>(
        t1b, ln1_g + i * DMODEL, ln1_b + i * DMODEL, hb);

    // FFN1 on the 128x128 tile (N=2048)
    gemm128<1, 0><<<dim3(16, 32), 256, 0, stream>>>(
        hb, wtL + 1048576, b1 + i * DFF, nullptr, nullptr, ffh, 512, 2048, 0);
    // t1b = ffh @ W2 + b2 + hb  (residual fused)
    gemm64<0, 1, 0, 1><<<dim3(8, 64), 256, 0, stream>>>(
        ffh, wtL + 2097152, b2 + i * DMODEL, (void*)t1b, hb, 2048, 512);
    ln_kernel<<<dim3(ROWS / 4), 256, 0, stream>>>(
        t1b, ln2_g + i * DMODEL, ln2_b + i * DMODEL, hb);
  }

  gemm64<0, 0, 0, 0><<<dim3(1, 64), 256, 0, stream>>>(
      hb, wdecT, b_dec, d_out, nullptr, 512, 64);
}

// Round 10
// 558.091 us; speedup vs baseline: 1.0105x; 1.0105x over previous
//
#include <hip/hip_runtime.h>
#include <math.h>

#define SEQ 1024
#define BATCH 4
#define DMODEL 512
#define NHEAD 8
#define DK 64
#define DFF 2048
#define U_TOP 34
#define ROWS (BATCH * SEQ)

typedef unsigned short ushort_t;
typedef __attribute__((ext_vector_type(8))) short short8;
typedef __attribute__((ext_vector_type(4))) float float4v;

__device__ inline ushort_t f2bf(float f) {
  unsigned u = __float_as_uint(f);
  unsigned r = u + 0x7fffu + ((u >> 16) & 1u);
  return (ushort_t)(r >> 16);
}
__device__ inline float bf2f(ushort_t u) {
  return __uint_as_float((unsigned)u << 16);
}
// ordered-uint key -> float (rare >64-candidate fallback only)
__device__ inline float keyinv(unsigned cand) {
  unsigned fb = (cand & 0x80000000u) ? (cand ^ 0x80000000u) : ~cand;
  return __uint_as_float(fb);
}

union H16 { _Float16 h; unsigned short u; };
__device__ inline unsigned short h2u(float f) {
  H16 t; t.h = (_Float16)f; return t.u;
}
__device__ inline float u2h(unsigned short u) {
  H16 t; t.u = u; return (float)t.h;
}
__device__ inline int mbcnt64(unsigned long long m) {
  int lo = __builtin_amdgcn_mbcnt_lo((unsigned)m, 0);
  return __builtin_amdgcn_mbcnt_hi((unsigned)(m >> 32), lo);
}

__device__ inline void glds16(const void* g, void* l) {
  __builtin_amdgcn_global_load_lds(
      (const __attribute__((address_space(1))) unsigned int*)g,
      (__attribute__((address_space(3))) unsigned int*)l, 16, 0, 0);
}

// Descending bitonic sort of TWO independent values/lane.
__device__ inline void bitonic64x2(float& a, float& b, int lane) {
#pragma unroll
  for (int k = 2; k <= 64; k <<= 1) {
#pragma unroll
    for (int j = k >> 1; j > 0; j >>= 1) {
      float pa = __shfl_xor(a, j);
      float pb = __shfl_xor(b, j);
      bool keepMin = (((lane & k) != 0) == ((lane & j) == 0));
      a = keepMin ? fminf(a, pa) : fmaxf(a, pa);
      b = keepMin ? fminf(b, pb) : fmaxf(b, pb);
    }
  }
}

// ---------------------------------------------------------------------------
// bf16 MFMA GEMM, m97 structure: 128x128 tile, BK=32, 256 thr = 2x2 waves.
// SPLIT=1 (QKV): Bt has 1536 rows (Wq|Wk|Wv); z=bn>>9 routes output/bias.
// ---------------------------------------------------------------------------
template <int RELU, int SPLIT>
__global__ __launch_bounds__(256) void gemm128(
    const ushort_t* __restrict__ A, const short* __restrict__ Bt,
    const float* __restrict__ b0, const float* __restrict__ b1,
    const float* __restrict__ b2, ushort_t* __restrict__ Cout,
    int K, int N, int zCstride) {
  __shared__ short As[128 * 32];
  __shared__ short Bs[128 * 32];

  const int tid = threadIdx.x;
  const int lane = tid & 63, w = tid >> 6;
  const int wm = w >> 1, wn = w & 1;
  const int quad = lane >> 4, r16 = lane & 15;
  const int bm = blockIdx.y * 128, bn = blockIdx.x * 128;

  const int srow = lane >> 2, skseg = lane & 3;
  const ushort_t* Ag0 = A + (size_t)(bm + w * 16 + srow) * K + skseg * 8;
  const ushort_t* Ag1 = Ag0 + (size_t)64 * K;
  const short* Bg0 = Bt + (size_t)(bn + w * 16 + srow) * K + skseg * 8;
  const short* Bg1 = Bg0 + (size_t)64 * K;
  short* lA0 = As + (w * 16) * 32;
  short* lA1 = As + (64 + w * 16) * 32;
  short* lB0 = Bs + (w * 16) * 32;
  short* lB1 = Bs + (64 + w * 16) * 32;

  float4v acc[4][4];
#pragma unroll
  for (int m = 0; m < 4; ++m)
#pragma unroll
    for (int n = 0; n < 4; ++n) acc[m][n] = (float4v){0.f, 0.f, 0.f, 0.f};

  for (int k0 = 0; k0 < K; k0 += 32) {
    __syncthreads();
    glds16(Ag0 + k0, lA0);
    glds16(Ag1 + k0, lA1);
    glds16(Bg0 + k0, lB0);
    glds16(Bg1 + k0, lB1);
    __syncthreads();

    short8 af[4], bfr[4];
#pragma unroll
    for (int m = 0; m < 4; ++m)
      af[m] = *(const short8*)&As[(wm * 64 + m * 16 + r16) * 32 + quad * 8];
#pragma unroll
    for (int n = 0; n < 4; ++n)
      bfr[n] = *(const short8*)&Bs[(wn * 64 + n * 16 + r16) * 32 + quad * 8];
#pragma unroll
    for (int m = 0; m < 4; ++m)
#pragma unroll
      for (int n = 0; n < 4; ++n)
        acc[m][n] = __builtin_amdgcn_mfma_f32_16x16x32_bf16(af[m], bfr[n],
                                                            acc[m][n], 0, 0, 0);
  }

  const int z = SPLIT ? (bn >> 9) : 0;
  const float* bias = (z == 0) ? b0 : (z == 1 ? b1 : b2);
  const int cbase = SPLIT ? (bn & 511) : bn;
  const int strideN = SPLIT ? 512 : N;
  ushort_t* C = Cout + (SPLIT ? (size_t)z * zCstride : (size_t)0);

  float bias_n[4];
#pragma unroll
  for (int n = 0; n < 4; ++n)
    bias_n[n] = bias[cbase + wn * 64 + n * 16 + r16];

#pragma unroll
  for (int m = 0; m < 4; ++m) {
#pragma unroll
    for (int n = 0; n < 4; ++n) {
      int col = cbase + wn * 64 + n * 16 + r16;
#pragma unroll
      for (int reg = 0; reg < 4; ++reg) {
        int row = bm + wm * 64 + m * 16 + quad * 4 + reg;
        float v = acc[m][n][reg] + bias_n[n];
        if (RELU) v = fmaxf(v, 0.f);
        C[(size_t)row * strideN + col] = f2bf(v);
      }
    }
  }
}

// ---------------------------------------------------------------------------
// Split-K bf16 MFMA GEMM, 128x128 tile over K-range [z*Ks, (z+1)*Ks).
// Writes bf16 partials to pout + z*2097152 (N fixed 512). Bias on z==0.
// Grid (N/128, M/128, 2) = 256 blocks = 1/CU for N=512.
// ---------------------------------------------------------------------------
__global__ __launch_bounds__(256) void gemm128sk(
    const ushort_t* __restrict__ A, const short* __restrict__ Bt,
    const float* __restrict__ bias, ushort_t* __restrict__ pout,
    int K, int Ks) {
  __shared__ short As[128 * 32];
  __shared__ short Bs[128 * 32];

  const int tid = threadIdx.x;
  const int lane = tid & 63, w = tid >> 6;
  const int wm = w >> 1, wn = w & 1;
  const int quad = lane >> 4, r16 = lane & 15;
  const int bm = blockIdx.y * 128, bn = blockIdx.x * 128;
  const int z = blockIdx.z;
  const int koff = z * Ks;

  const int srow = lane >> 2, skseg = lane & 3;
  const ushort_t* Ag0 =
      A + (size_t)(bm + w * 16 + srow) * K + skseg * 8 + koff;
  const ushort_t* Ag1 = Ag0 + (size_t)64 * K;
  const short* Bg0 = Bt + (size_t)(bn + w * 16 + srow) * K + skseg * 8 + koff;
  const short* Bg1 = Bg0 + (size_t)64 * K;
  short* lA0 = As + (w * 16) * 32;
  short* lA1 = As + (64 + w * 16) * 32;
  short* lB0 = Bs + (w * 16) * 32;
  short* lB1 = Bs + (64 + w * 16) * 32;

  float4v acc[4][4];
#pragma unroll
  for (int m = 0; m < 4; ++m)
#pragma unroll
    for (int n = 0; n < 4; ++n) acc[m][n] = (float4v){0.f, 0.f, 0.f, 0.f};

  for (int k0 = 0; k0 < Ks; k0 += 32) {
    __syncthreads();
    glds16(Ag0 + k0, lA0);
    glds16(Ag1 + k0, lA1);
    glds16(Bg0 + k0, lB0);
    glds16(Bg1 + k0, lB1);
    __syncthreads();

    short8 af[4], bfr[4];
#pragma unroll
    for (int m = 0; m < 4; ++m)
      af[m] = *(const short8*)&As[(wm * 64 + m * 16 + r16) * 32 + quad * 8];
#pragma unroll
    for (int n = 0; n < 4; ++n)
      bfr[n] = *(const short8*)&Bs[(wn * 64 + n * 16 + r16) * 32 + quad * 8];
#pragma unroll
    for (int m = 0; m < 4; ++m)
#pragma unroll
      for (int n = 0; n < 4; ++n)
        acc[m][n] = __builtin_amdgcn_mfma_f32_16x16x32_bf16(af[m], bfr[n],
                                                            acc[m][n], 0, 0, 0);
  }

  ushort_t* P = pout + (size_t)z * 2097152;
  float bias_n[4];
#pragma unroll
  for (int n = 0; n < 4; ++n)
    bias_n[n] = (z == 0) ? bias[bn + wn * 64 + n * 16 + r16] : 0.f;

#pragma unroll
  for (int m = 0; m < 4; ++m) {
#pragma unroll
    for (int n = 0; n < 4; ++n) {
      int col = bn + wn * 64 + n * 16 + r16;
#pragma unroll
      for (int reg = 0; reg < 4; ++reg) {
        int row = bm + wm * 64 + m * 16 + quad * 4 + reg;
        float v = acc[m][n][reg] + bias_n[n];
        P[(size_t)row * 512 + col] = f2bf(v);
      }
    }
  }
}

// ---------------------------------------------------------------------------
// bf16 MFMA GEMM, tile 64x64 (embed + decode only).
// EPI 0: none. EPI 2: v = v*sqrt(512) + positional encoding (embed).
// ---------------------------------------------------------------------------
template <int RELU, int OUTBF16, int EPI, int ADDC>
__global__ __launch_bounds__(256) void gemm64(
    const ushort_t* __restrict__ A, const short* __restrict__ Bt,
    const float* __restrict__ bias, void* __restrict__ Cout,
    const ushort_t* __restrict__ Cadd, int K, int N) {
  __shared__ short As[64 * 32];
  __shared__ short Bs[64 * 32];

  const int tid = threadIdx.x;
  const int lane = tid & 63, w = tid >> 6;
  const int wm = w >> 1, wn = w & 1;
  const int quad = lane >> 4, r16 = lane & 15;
  const int bm = blockIdx.y * 64, bn = blockIdx.x * 64;

  const int srow = tid >> 2, skseg = tid & 3;
  const ushort_t* Ag = A + (size_t)(bm + srow) * K + skseg * 8;
  const short* Bg = Bt + (size_t)(bn + srow) * K + skseg * 8;
  short* lA = As + w * 512;
  short* lB = Bs + w * 512;

  float4v acc[2][2];
#pragma unroll
  for (int m = 0; m < 2; ++m)
#pragma unroll
    for (int n = 0; n < 2; ++n) acc[m][n] = (float4v){0.f, 0.f, 0.f, 0.f};

  for (int k0 = 0; k0 < K; k0 += 32) {
    __syncthreads();
    glds16(Ag + k0, lA);
    glds16(Bg + k0, lB);
    __syncthreads();

    short8 af[2], bfr[2];
#pragma unroll
    for (int m = 0; m < 2; ++m)
      af[m] = *(const short8*)&As[(wm * 32 + m * 16 + r16) * 32 + quad * 8];
#pragma unroll
    for (int n = 0; n < 2; ++n)
      bfr[n] = *(const short8*)&Bs[(wn * 32 + n * 16 + r16) * 32 + quad * 8];
#pragma unroll
    for (int m = 0; m < 2; ++m)
#pragma unroll
      for (int n = 0; n < 2; ++n)
        acc[m][n] = __builtin_amdgcn_mfma_f32_16x16x32_bf16(af[m], bfr[n],
                                                            acc[m][n], 0, 0, 0);
  }

  const float pe_c = (float)(-9.210340371976184 / 512.0);
  const float sqrtd = 22.62741699796952f;

  float bias_n[2];
#pragma unroll
  for (int n = 0; n < 2; ++n) bias_n[n] = bias[bn + wn * 32 + n * 16 + r16];

#pragma unroll
  for (int m = 0; m < 2; ++m) {
#pragma unroll
    for (int n = 0; n < 2; ++n) {
      int col = bn + wn * 32 + n * 16 + r16;
#pragma unroll
      for (int reg = 0; reg < 4; ++reg) {
        int row = bm + wm * 32 + m * 16 + quad * 4 + reg;
        float v = acc[m][n][reg] + bias_n[n];
        if (RELU) v = fmaxf(v, 0.f);
        if (EPI == 2) {
          int pos = row & (SEQ - 1);
          float e = __expf((float)(col & ~1) * pe_c);
          float arg = (float)pos * e;
          v = v * sqrtd + ((col & 1) ? __cosf(arg) : __sinf(arg));
        }
        if (ADDC) v += bf2f(Cadd[(size_t)row * N + col]);
        if (OUTBF16) {
          ((ushort_t*)Cout)[(size_t)row * N + col] = f2bf(v);
        } else {
          ((float*)Cout)[(size_t)row * N + col] = v;
        }
      }
    }
  }
}

// ---------------------------------------------------------------------------
// All weights (3 layers + emb + dec): W[K][N] f32 -> Wt[N][K] bf16, 1 launch.
// ---------------------------------------------------------------------------
__global__ __launch_bounds__(256) void convert_all(
    const float* __restrict__ Wq, const float* __restrict__ Wk,
    const float* __restrict__ Wv, const float* __restrict__ Wo,
    const float* __restrict__ W1, const float* __restrict__ W2,
    const float* __restrict__ W_emb, const float* __restrict__ W_dec,
    short* __restrict__ wt) {
  __shared__ float t[32][33];
  int id = blockIdx.x;
  const float* src;
  short* dst;
  int K, N, tk, tn;
  if (id < 9216) {
    int lay = id / 3072, r = id % 3072;
    short* wl = wt + (size_t)lay * 3145728;
    const size_t wsz = 512 * 512;
    if (r < 1024) {
      int wi = r >> 8, tile = r & 255;
      const float* base = (wi == 0) ? Wq : (wi == 1) ? Wk : (wi == 2) ? Wv : Wo;
      src = base + lay * wsz;
      dst = wl + wi * 262144;
      K = 512; N = 512; tk = tile >> 4; tn = tile & 15;
    } else if (r < 2048) {
      int tile = r - 1024;
      src = W1 + (size_t)lay * 512 * 2048;
      dst = wl + 1048576;
      K = 512; N = 2048; tk = tile >> 6; tn = tile & 63;
    } else {
      int tile = r - 2048;
      src = W2 + (size_t)lay * 2048 * 512;
      dst = wl + 2097152;
      K = 2048; N = 512; tk = tile >> 4; tn = tile & 15;
    }
  } else {
    int r = id - 9216;
    if (r < 64) {
      src = W_emb; dst = wt + 9437184; K = 128; N = 512; tk = r >> 4; tn = r & 15;
    } else {
      r -= 64;
      src = W_dec; dst = wt + 9502720; K = 512; N = 64; tk = r >> 1; tn = r & 1;
    }
  }
  const int k0 = tk * 32, n0 = tn * 32;
  const int tx = threadIdx.x, ty = threadIdx.y;
#pragma unroll
  for (int i = 0; i < 4; ++i) {
    int r = ty + i * 8;
    t[r][tx] = src[(size_t)(k0 + r) * N + n0 + tx];
  }
  __syncthreads();
#pragma unroll
  for (int i = 0; i < 4; ++i) {
    int r = ty + i * 8;
    dst[(size_t)(n0 + r) * K + k0 + tx] = (short)f2bf(t[tx][r]);
  }
}

__global__ __launch_bounds__(256) void f32_to_bf16_kernel(
    const float* __restrict__ src, ushort_t* __restrict__ dst) {
  int i = blockIdx.x * blockDim.x + threadIdx.x;
  float4 v = ((const float4*)src)[i];
  ushort4 o;
  o.x = f2bf(v.x); o.y = f2bf(v.y); o.z = f2bf(v.z); o.w = f2bf(v.w);
  ((ushort4*)dst)[i] = o;
}

// ---------------------------------------------------------------------------
// Split-K reduce + residual + LayerNorm: hb = LN(pa + pb + hb) * g + b.
// One wave per row; lane owns 8 contiguous cols.
// ---------------------------------------------------------------------------
__global__ __launch_bounds__(256) void ln_red_kernel(
    const ushort_t* __restrict__ pa, const ushort_t* __restrict__ pb,
    const float* __restrict__ g, const float* __restrict__ bb,
    ushort_t* __restrict__ hb) {
  const int row = blockIdx.x * 4 + (threadIdx.x >> 6);
  const int lane = threadIdx.x & 63;
  const size_t base = (size_t)row * DMODEL + lane * 8;
  uint4 ra = *(const uint4*)(pa + base);
  uint4 rb = *(const uint4*)(pb + base);
  uint4 rh = *(const uint4*)(hb + base);
  unsigned aa[4] = {ra.x, ra.y, ra.z, ra.w};
  unsigned ab[4] = {rb.x, rb.y, rb.z, rb.w};
  unsigned ah[4] = {rh.x, rh.y, rh.z, rh.w};
  float v[8];
#pragma unroll
  for (int k = 0; k < 4; ++k) {
    v[2 * k] = bf2f((ushort_t)(aa[k] & 0xffff)) +
               bf2f((ushort_t)(ab[k] & 0xffff)) +
               bf2f((ushort_t)(ah[k] & 0xffff));
    v[2 * k + 1] = bf2f((ushort_t)(aa[k] >> 16)) +
                   bf2f((ushort_t)(ab[k] >> 16)) +
                   bf2f((ushort_t)(ah[k] >> 16));
  }
  float sum = 0.f, sq = 0.f;
#pragma unroll
  for (int k = 0; k < 8; ++k) { sum += v[k]; sq += v[k] * v[k]; }
#pragma unroll
  for (int off = 32; off; off >>= 1) {
    sum += __shfl_xor(sum, off);
    sq += __shfl_xor(sq, off);
  }
  float mean = sum * (1.f / 512.f);
  float var = fmaxf(sq * (1.f / 512.f) - mean * mean, 0.f);
  float rstd = 1.f / sqrtf(var + 1e-5f);
  float4 g0 = *(const float4*)(g + lane * 8);
  float4 g1 = *(const float4*)(g + lane * 8 + 4);
  float4 c0 = *(const float4*)(bb + lane * 8);
  float4 c1 = *(const float4*)(bb + lane * 8 + 4);
  float gg[8] = {g0.x, g0.y, g0.z, g0.w, g1.x, g1.y, g1.z, g1.w};
  float cc[8] = {c0.x, c0.y, c0.z, c0.w, c1.x, c1.y, c1.z, c1.w};
  uint4 out;
  unsigned* op = (unsigned*)&out;
#pragma unroll
  for (int k = 0; k < 4; ++k) {
    float y0 = (v[2 * k] - mean) * rstd * gg[2 * k] + cc[2 * k];
    float y1 = (v[2 * k + 1] - mean) * rstd * gg[2 * k + 1] + cc[2 * k + 1];
    op[k] = (unsigned)f2bf(y0) | ((unsigned)f2bf(y1) << 16);
  }
  *(uint4*)(hb + base) = out;
}

// ---------------------------------------------------------------------------
// ProbSparse attention v8 (unchanged from R9).
// ---------------------------------------------------------------------------
#define SST 1048

__global__ __launch_bounds__(512, 8) void attn_kernel(
    const ushort_t* __restrict__ Qb, const ushort_t* __restrict__ Kb,
    const ushort_t* __restrict__ Vb, ushort_t* __restrict__ Ob) {
  __shared__ _Float16 s16[16 * SST];
  __shared__ unsigned plist[16][64];

  const int tid = threadIdx.x;
  const int q0 = blockIdx.x * 16;
  const int h = blockIdx.y;
  const int b = blockIdx.z;
  const int w = tid >> 6;
  const int lane = tid & 63;
  const int quad = lane >> 4, r16 = lane & 15;

  // ---- Phase 1: MFMA scores (16 queries x 128 keys per wave) ----
  {
    const int j0 = w * 128;
    const ushort_t* qrow =
        Qb + (size_t)(b * SEQ + q0 + r16) * DMODEL + h * DK + quad * 8;
    short8 aq0 = *(const short8*)qrow;
    short8 aq1 = *(const short8*)(qrow + 32);

#pragma unroll
    for (int nt = 0; nt < 8; ++nt) {
      const ushort_t* krow =
          Kb + (size_t)(b * SEQ + j0 + nt * 16 + r16) * DMODEL + h * DK +
          quad * 8;
      short8 bk0 = *(const short8*)krow;
      short8 bk1 = *(const short8*)(krow + 32);
      float4v a = (float4v){0.f, 0.f, 0.f, 0.f};
      a = __builtin_amdgcn_mfma_f32_16x16x32_bf16(aq0, bk0, a, 0, 0, 0);
      a = __builtin_amdgcn_mfma_f32_16x16x32_bf16(aq1, bk1, a, 0, 0, 0);
#pragma unroll
      for (int reg = 0; reg < 4; ++reg)
        s16[(quad * 4 + reg) * SST + j0 + nt * 16 + r16] =
            (_Float16)(a[reg] * 0.125f);
    }
  }
  __syncthreads();

  // ---- Phase 2: two queries per wave, interleaved chains ----
  {
    const int qa = w, qb2 = w + 8;
    const _Float16* sa = &s16[qa * SST];
    const _Float16* sb = &s16[qb2 * SST];

    float la = -1e30f, lb = -1e30f;
#pragma unroll
    for (int i = 0; i < 16; ++i) {
      la = fmaxf(la, (float)sa[lane + 64 * i]);
      lb = fmaxf(lb, (float)sb[lane + 64 * i]);
    }

    float sva = la, svb = lb;
    bitonic64x2(sva, svb, lane);
    const float mxa = __shfl(sva, 0), mxb = __shfl(svb, 0);
    const float fTa = __shfl(sva, 33), fTb = __shfl(svb, 33);

    int ca = 0, cb = 0;
#pragma unroll
    for (int i = 0; i < 16; ++i) {
      float va = (float)sa[lane + 64 * i];
      float vb = (float)sb[lane + 64 * i];
      bool ka = va >= fTa, kb = vb >= fTb;
      unsigned long long ma = __ballot(ka);
      unsigned long long mb = __ballot(kb);
      if (ka) {
        int p = ca + mbcnt64(ma);
        if (p < 64)
          plist[qa][p] = ((unsigned)(lane + 64 * i) << 16) |
                         h2u(__expf(va - mxa));
      }
      if (kb) {
        int p = cb + mbcnt64(mb);
        if (p < 64)
          plist[qb2][p] = ((unsigned)(lane + 64 * i) << 16) |
                          h2u(__expf(vb - mxb));
      }
      ca += (int)__popcll(ma);
      cb += (int)__popcll(mb);
    }

    if (__builtin_expect(ca > 64, 0)) {
      unsigned ans = 0u;
      int cge = ca;
      bool ex = false;
      for (int bit = 31; bit >= 0 && cge > 64 && !ex; --bit) {
        unsigned cand = ans | (1u << bit);
        float fc = keyinv(cand);
        int c = 0;
#pragma unroll
        for (int i = 0; i < 16; ++i)
          c += (int)__popcll(__ballot((float)sa[lane + 64 * i] >= fc));
        if (c >= U_TOP) { ans = cand; cge = c; ex = (c == U_TOP); }
      }
      float fa2 = keyinv(ans);
      int cc = 0;
#pragma unroll
      for (int i = 0; i < 16; ++i) {
        float va = (float)sa[lane + 64 * i];
        bool ka = va >= fa2;
        unsigned long long ma = __ballot(ka);
        if (ka) {
          int p = cc + mbcnt64(ma);
          if (p < 64)
            plist[qa][p] = ((unsigned)(lane + 64 * i) << 16) |
                           h2u(__expf(va - mxa));
        }
        cc += (int)__popcll(ma);
      }
      ca = cc;
    }
    if (__builtin_expect(cb > 64, 0)) {
      unsigned ans = 0u;
      int cge = cb;
      bool ex = false;
      for (int bit = 31; bit >= 0 && cge > 64 && !ex; --bit) {
        unsigned cand = ans | (1u << bit);
        float fc = keyinv(cand);
        int c = 0;
#pragma unroll
        for (int i = 0; i < 16; ++i)
          c += (int)__popcll(__ballot((float)sb[lane + 64 * i] >= fc));
        if (c >= U_TOP) { ans = cand; cge = c; ex = (c == U_TOP); }
      }
      float fb2 = keyinv(ans);
      int cc = 0;
#pragma unroll
      for (int i = 0; i < 16; ++i) {
        float vb = (float)sb[lane + 64 * i];
        bool kb = vb >= fb2;
        unsigned long long mb = __ballot(kb);
        if (kb) {
          int p = cc + mbcnt64(mb);
          if (p < 64)
            plist[qb2][p] = ((unsigned)(lane + 64 * i) << 16) |
                            h2u(__expf(vb - mxb));
        }
        cc += (int)__popcll(mb);
      }
      cb = cc;
    }
    ca = ca > 64 ? 64 : ca;
    cb = cb > 64 ? 64 : cb;

    unsigned pua = (lane < ca) ? plist[qa][lane] : 0u;
    unsigned pub = (lane < cb) ? plist[qb2][lane] : 0u;
    float ea = u2h((unsigned short)(pua & 0xffffu));
    float eb = u2h((unsigned short)(pub & 0xffffu));

    float s2a = ea, s2b = eb;
    bitonic64x2(s2a, s2b, lane);
    const float tha = __shfl(s2a, 33), thb = __shfl(s2b, 33);

    bool keepa = ea >= tha, keepb = eb >= thb;
    unsigned long long kma = __ballot(keepa);
    unsigned long long kmb = __ballot(keepb);
    int na = (int)__popcll(kma), nb = (int)__popcll(kmb);
    float za = keepa ? ea : 0.f, zb = keepb ? eb : 0.f;
#pragma unroll
    for (int off = 32; off; off >>= 1) {
      za += __shfl_xor(za, off);
      zb += __shfl_xor(zb, off);
    }
    int posa = mbcnt64(kma), posb = mbcnt64(kmb);
    if (keepa) plist[qa][posa] = pua;
    if (keepb) plist[qb2][posb] = pub;

    const ushort_t* vbase = Vb + (size_t)b * SEQ * DMODEL + h * DK;
    float oa = 0.f, ob = 0.f;
    int nmax = na > nb ? na : nb;
    for (int i = 0; i < nmax; i += 2) {
      unsigned ua0 = (i < na) ? plist[qa][i] : 0u;
      unsigned ua1 = (i + 1 < na) ? plist[qa][i + 1] : 0u;
      unsigned ub0 = (i < nb) ? plist[qb2][i] : 0u;
      unsigned ub1 = (i + 1 < nb) ? plist[qb2][i + 1] : 0u;
      float pa0 = bf2f(vbase[(size_t)(ua0 >> 16) * DMODEL + lane]);
      float pa1 = bf2f(vbase[(size_t)(ua1 >> 16) * DMODEL + lane]);
      float pb0 = bf2f(vbase[(size_t)(ub0 >> 16) * DMODEL + lane]);
      float pb1 = bf2f(vbase[(size_t)(ub1 >> 16) * DMODEL + lane]);
      oa += u2h((unsigned short)(ua0 & 0xffffu)) * pa0 +
            u2h((unsigned short)(ua1 & 0xffffu)) * pa1;
      ob += u2h((unsigned short)(ub0 & 0xffffu)) * pb0 +
            u2h((unsigned short)(ub1 & 0xffffu)) * pb1;
    }
    oa /= za;
    ob /= zb;
    Ob[(size_t)(b * SEQ + q0 + qa) * DMODEL + h * DK + lane] = f2bf(oa);
    Ob[(size_t)(b * SEQ + q0 + qb2) * DMODEL + h * DK + lane] = f2bf(ob);
  }
}

// ---------------------------------------------------------------------------
// Orchestration.  ws layout (MiB): ffh/qkv [0,16) (Wo partials reuse [0,8)
// after attn) | ao [16,20) (xb pre-loop; FFN2 partials reuse [16,24)) |
// [20,24) FFN2 partial 1 | hb [24,28) | wt [28, 46.2).
// ---------------------------------------------------------------------------
extern "C" void kernel_launch(void* const* d_in, const int* in_sizes, int n_in,
                              void* d_out, int out_size, void* d_ws,
                              size_t ws_size, hipStream_t stream) {
  const float* x = (const float*)d_in[0];
  const float* W_emb = (const float*)d_in[1];
  const float* b_emb = (const float*)d_in[2];
  const float* Wq = (const float*)d_in[3];
  const float* bq = (const float*)d_in[4];
  const float* Wk = (const float*)d_in[5];
  const float* bk = (const float*)d_in[6];
  const float* Wv = (const float*)d_in[7];
  const float* bv = (const float*)d_in[8];
  const float* Wo = (const float*)d_in[9];
  const float* bo = (const float*)d_in[10];
  const float* ln1_g = (const float*)d_in[11];
  const float* ln1_b = (const float*)d_in[12];
  const float* W1 = (const float*)d_in[13];
  const float* b1 = (const float*)d_in[14];
  const float* W2 = (const float*)d_in[15];
  const float* b2 = (const float*)d_in[16];
  const float* ln2_g = (const float*)d_in[17];
  const float* ln2_b = (const float*)d_in[18];
  const float* W_dec = (const float*)d_in[19];
  const float* b_dec = (const float*)d_in[20];

  char* wsb = (char*)d_ws;
  ushort_t* qkv = (ushort_t*)wsb;
  ushort_t* ffh = (ushort_t*)wsb;
  ushort_t* wop = (ushort_t*)wsb;  // Wo partials [0,8M): z0 @0, z1 @4M
  ushort_t* ao = (ushort_t*)(wsb + ((size_t)16 << 20));
  ushort_t* xb = (ushort_t*)(wsb + ((size_t)16 << 20));
  ushort_t* ffp = (ushort_t*)(wsb + ((size_t)16 << 20));  // FFN2 partials
  ushort_t* hb = (ushort_t*)(wsb + ((size_t)24 << 20));
  short* wt = (short*)(wsb + ((size_t)28 << 20));
  short* wembT = wt + 9437184;
  short* wdecT = wt + 9502720;

  f32_to_bf16_kernel<<<dim3(512), 256, 0, stream>>>(x, xb);
  convert_all<<<dim3(9312), dim3(32, 8), 0, stream>>>(Wq, Wk, Wv, Wo, W1, W2,
                                                      W_emb, W_dec, wt);
  // embed: hb = bf16((xb @ W_emb + b_emb)*sqrt(512) + PE)
  gemm64<0, 1, 2, 0><<<dim3(8, 64), 256, 0, stream>>>(
      xb, wembT, b_emb, (void*)hb, nullptr, 128, 512);

  for (int i = 0; i < 3; ++i) {
    short* wtL = wt + (size_t)i * 3145728;

    // QKV: one N=1536 GEMM on the 128x128 tile, z-split epilogue
    gemm128<0, 1><<<dim3(12, 32), 256, 0, stream>>>(
        hb, wtL, bq + i * DMODEL, bk + i * DMODEL, bv + i * DMODEL, qkv, 512,
        512, 2097152);

    attn_kernel<<<dim3(SEQ / 16, NHEAD, BATCH), dim3(512), 0, stream>>>(
        qkv, qkv + 2097152, qkv + 4194304, ao);

    // Wo split-K (K=512 -> 2x256): partials over dead qkv region
    gemm128sk<<<dim3(4, 32, 2), 256, 0, stream>>>(
        ao, wtL + 786432, bo + i * DMODEL, wop, 512, 256);
    ln_red_kernel<<<dim3(ROWS / 4), 256, 0, stream>>>(
        wop, wop + 2097152, ln1_g + i * DMODEL, ln1_b + i * DMODEL, hb);

    // FFN1 on the 128x128 tile (N=2048): overwrites wop (dead)
    gemm128<1, 0><<<dim3(16, 32), 256, 0, stream>>>(
        hb, wtL + 1048576, b1 + i * DFF, nullptr, nullptr, ffh, 512, 2048, 0);
    // FFN2 split-K (K=2048 -> 2x1024): partials over dead ao region
    gemm128sk<<<dim3(4, 32, 2), 256, 0, stream>>>(
        ffh, wtL + 2097152, b2 + i * DMODEL, ffp, 2048, 1024);
    ln_red_kernel<<<dim3(ROWS / 4), 256, 0, stream>>>(
        ffp, ffp + 2097152, ln2_g + i * DMODEL, ln2_b + i * DMODEL, hb);
  }

  gemm64<0, 0, 0, 0><<<dim3(1, 64), 256, 0, stream>>>(
      hb, wdecT, b_dec, d_out, nullptr, 512, 64);
}

// Round 11
// 553.223 us; speedup vs baseline: 1.0194x; 1.0088x over previous
//
#include <hip/hip_runtime.h>
#include <math.h>

#define SEQ 1024
#define BATCH 4
#define DMODEL 512
#define NHEAD 8
#define DK 64
#define DFF 2048
#define U_TOP 34
#define ROWS (BATCH * SEQ)

typedef unsigned short ushort_t;
typedef __attribute__((ext_vector_type(8))) short short8;
typedef __attribute__((ext_vector_type(4))) float float4v;

__device__ inline ushort_t f2bf(float f) {
  unsigned u = __float_as_uint(f);
  unsigned r = u + 0x7fffu + ((u >> 16) & 1u);
  return (ushort_t)(r >> 16);
}
__device__ inline float bf2f(ushort_t u) {
  return __uint_as_float((unsigned)u << 16);
}
// ordered-uint key -> float (rare >64-candidate fallback only)
__device__ inline float keyinv(unsigned cand) {
  unsigned fb = (cand & 0x80000000u) ? (cand ^ 0x80000000u) : ~cand;
  return __uint_as_float(fb);
}

union H16 { _Float16 h; unsigned short u; };
__device__ inline unsigned short h2u(float f) {
  H16 t; t.h = (_Float16)f; return t.u;
}
__device__ inline float u2h(unsigned short u) {
  H16 t; t.u = u; return (float)t.h;
}
__device__ inline float lo16(unsigned u) { return u2h((unsigned short)(u & 0xffffu)); }
__device__ inline float hi16(unsigned u) { return u2h((unsigned short)(u >> 16)); }
__device__ inline int mbcnt64(unsigned long long m) {
  int lo = __builtin_amdgcn_mbcnt_lo((unsigned)m, 0);
  return __builtin_amdgcn_mbcnt_hi((unsigned)(m >> 32), lo);
}

__device__ inline void glds16(const void* g, void* l) {
  __builtin_amdgcn_global_load_lds(
      (const __attribute__((address_space(1))) unsigned int*)g,
      (__attribute__((address_space(3))) unsigned int*)l, 16, 0, 0);
}

// Descending bitonic sort of TWO independent values/lane.
__device__ inline void bitonic64x2(float& a, float& b, int lane) {
#pragma unroll
  for (int k = 2; k <= 64; k <<= 1) {
#pragma unroll
    for (int j = k >> 1; j > 0; j >>= 1) {
      float pa = __shfl_xor(a, j);
      float pb = __shfl_xor(b, j);
      bool keepMin = (((lane & k) != 0) == ((lane & j) == 0));
      a = keepMin ? fminf(a, pa) : fmaxf(a, pa);
      b = keepMin ? fminf(b, pb) : fmaxf(b, pb);
    }
  }
}

// ---------------------------------------------------------------------------
// bf16 MFMA GEMM, m97 structure: 128x128 tile, BK=32, 256 thr = 2x2 waves.
// XCD swizzle: each XCD owns a band of row-tiles (A fetched once per band).
// SPLIT=1 (QKV): Bt has 1536 rows (Wq|Wk|Wv); z=bn>>9 routes output/bias.
// Requires gridDim.y % 8 == 0.
// ---------------------------------------------------------------------------
template <int RELU, int SPLIT>
__global__ __launch_bounds__(256) void gemm128(
    const ushort_t* __restrict__ A, const short* __restrict__ Bt,
    const float* __restrict__ b0, const float* __restrict__ b1,
    const float* __restrict__ b2, ushort_t* __restrict__ Cout,
    int K, int N, int zCstride) {
  __shared__ short As[128 * 32];
  __shared__ short Bs[128 * 32];

  const int tid = threadIdx.x;
  const int lane = tid & 63, w = tid >> 6;
  const int wm = w >> 1, wn = w & 1;
  const int quad = lane >> 4, r16 = lane & 15;

  // XCD-affinity block swizzle (round-robin id%8 -> XCD heuristic)
  const int id = blockIdx.y * gridDim.x + blockIdx.x;
  const int xcd = id & 7;
  const int loc = id >> 3;
  const int rpx = gridDim.y >> 3;  // row-tiles per XCD
  const int bm = (xcd * rpx + (loc % rpx)) * 128;
  const int bn = (loc / rpx) * 128;

  const int srow = lane >> 2, skseg = lane & 3;
  const ushort_t* Ag0 = A + (size_t)(bm + w * 16 + srow) * K + skseg * 8;
  const ushort_t* Ag1 = Ag0 + (size_t)64 * K;
  const short* Bg0 = Bt + (size_t)(bn + w * 16 + srow) * K + skseg * 8;
  const short* Bg1 = Bg0 + (size_t)64 * K;
  short* lA0 = As + (w * 16) * 32;
  short* lA1 = As + (64 + w * 16) * 32;
  short* lB0 = Bs + (w * 16) * 32;
  short* lB1 = Bs + (64 + w * 16) * 32;

  float4v acc[4][4];
#pragma unroll
  for (int m = 0; m < 4; ++m)
#pragma unroll
    for (int n = 0; n < 4; ++n) acc[m][n] = (float4v){0.f, 0.f, 0.f, 0.f};

  for (int k0 = 0; k0 < K; k0 += 32) {
    __syncthreads();
    glds16(Ag0 + k0, lA0);
    glds16(Ag1 + k0, lA1);
    glds16(Bg0 + k0, lB0);
    glds16(Bg1 + k0, lB1);
    __syncthreads();

    short8 af[4], bfr[4];
#pragma unroll
    for (int m = 0; m < 4; ++m)
      af[m] = *(const short8*)&As[(wm * 64 + m * 16 + r16) * 32 + quad * 8];
#pragma unroll
    for (int n = 0; n < 4; ++n)
      bfr[n] = *(const short8*)&Bs[(wn * 64 + n * 16 + r16) * 32 + quad * 8];
#pragma unroll
    for (int m = 0; m < 4; ++m)
#pragma unroll
      for (int n = 0; n < 4; ++n)
        acc[m][n] = __builtin_amdgcn_mfma_f32_16x16x32_bf16(af[m], bfr[n],
                                                            acc[m][n], 0, 0, 0);
  }

  const int z = SPLIT ? (bn >> 9) : 0;
  const float* bias = (z == 0) ? b0 : (z == 1 ? b1 : b2);
  const int cbase = SPLIT ? (bn & 511) : bn;
  const int strideN = SPLIT ? 512 : N;
  ushort_t* C = Cout + (SPLIT ? (size_t)z * zCstride : (size_t)0);

  float bias_n[4];
#pragma unroll
  for (int n = 0; n < 4; ++n)
    bias_n[n] = bias[cbase + wn * 64 + n * 16 + r16];

#pragma unroll
  for (int m = 0; m < 4; ++m) {
#pragma unroll
    for (int n = 0; n < 4; ++n) {
      int col = cbase + wn * 64 + n * 16 + r16;
#pragma unroll
      for (int reg = 0; reg < 4; ++reg) {
        int row = bm + wm * 64 + m * 16 + quad * 4 + reg;
        float v = acc[m][n][reg] + bias_n[n];
        if (RELU) v = fmaxf(v, 0.f);
        C[(size_t)row * strideN + col] = f2bf(v);
      }
    }
  }
}

// ---------------------------------------------------------------------------
// Split-K bf16 MFMA GEMM, 128x128 tile over K-range [z*Ks, (z+1)*Ks).
// XCD swizzle on (x,y); z handled separately (no reuse across z anyway).
// Writes bf16 partials to pout + z*2097152 (N fixed 512). Bias on z==0.
// ---------------------------------------------------------------------------
__global__ __launch_bounds__(256) void gemm128sk(
    const ushort_t* __restrict__ A, const short* __restrict__ Bt,
    const float* __restrict__ bias, ushort_t* __restrict__ pout,
    int K, int Ks) {
  __shared__ short As[128 * 32];
  __shared__ short Bs[128 * 32];

  const int tid = threadIdx.x;
  const int lane = tid & 63, w = tid >> 6;
  const int wm = w >> 1, wn = w & 1;
  const int quad = lane >> 4, r16 = lane & 15;

  const int id = blockIdx.y * gridDim.x + blockIdx.x;
  const int xcd = id & 7;
  const int loc = id >> 3;
  const int rpx = gridDim.y >> 3;
  const int bm = (xcd * rpx + (loc % rpx)) * 128;
  const int bn = (loc / rpx) * 128;
  const int z = blockIdx.z;
  const int koff = z * Ks;

  const int srow = lane >> 2, skseg = lane & 3;
  const ushort_t* Ag0 =
      A + (size_t)(bm + w * 16 + srow) * K + skseg * 8 + koff;
  const ushort_t* Ag1 = Ag0 + (size_t)64 * K;
  const short* Bg0 = Bt + (size_t)(bn + w * 16 + srow) * K + skseg * 8 + koff;
  const short* Bg1 = Bg0 + (size_t)64 * K;
  short* lA0 = As + (w * 16) * 32;
  short* lA1 = As + (64 + w * 16) * 32;
  short* lB0 = Bs + (w * 16) * 32;
  short* lB1 = Bs + (64 + w * 16) * 32;

  float4v acc[4][4];
#pragma unroll
  for (int m = 0; m < 4; ++m)
#pragma unroll
    for (int n = 0; n < 4; ++n) acc[m][n] = (float4v){0.f, 0.f, 0.f, 0.f};

  for (int k0 = 0; k0 < Ks; k0 += 32) {
    __syncthreads();
    glds16(Ag0 + k0, lA0);
    glds16(Ag1 + k0, lA1);
    glds16(Bg0 + k0, lB0);
    glds16(Bg1 + k0, lB1);
    __syncthreads();

    short8 af[4], bfr[4];
#pragma unroll
    for (int m = 0; m < 4; ++m)
      af[m] = *(const short8*)&As[(wm * 64 + m * 16 + r16) * 32 + quad * 8];
#pragma unroll
    for (int n = 0; n < 4; ++n)
      bfr[n] = *(const short8*)&Bs[(wn * 64 + n * 16 + r16) * 32 + quad * 8];
#pragma unroll
    for (int m = 0; m < 4; ++m)
#pragma unroll
      for (int n = 0; n < 4; ++n)
        acc[m][n] = __builtin_amdgcn_mfma_f32_16x16x32_bf16(af[m], bfr[n],
                                                            acc[m][n], 0, 0, 0);
  }

  ushort_t* P = pout + (size_t)z * 2097152;
  float bias_n[4];
#pragma unroll
  for (int n = 0; n < 4; ++n)
    bias_n[n] = (z == 0) ? bias[bn + wn * 64 + n * 16 + r16] : 0.f;

#pragma unroll
  for (int m = 0; m < 4; ++m) {
#pragma unroll
    for (int n = 0; n < 4; ++n) {
      int col = bn + wn * 64 + n * 16 + r16;
#pragma unroll
      for (int reg = 0; reg < 4; ++reg) {
        int row = bm + wm * 64 + m * 16 + quad * 4 + reg;
        float v = acc[m][n][reg] + bias_n[n];
        P[(size_t)row * 512 + col] = f2bf(v);
      }
    }
  }
}

// ---------------------------------------------------------------------------
// bf16 MFMA GEMM, tile 64x64 (embed + decode only).
// EPI 0: none. EPI 2: v = v*sqrt(512) + positional encoding (embed).
// ---------------------------------------------------------------------------
template <int RELU, int OUTBF16, int EPI, int ADDC>
__global__ __launch_bounds__(256) void gemm64(
    const ushort_t* __restrict__ A, const short* __restrict__ Bt,
    const float* __restrict__ bias, void* __restrict__ Cout,
    const ushort_t* __restrict__ Cadd, int K, int N) {
  __shared__ short As[64 * 32];
  __shared__ short Bs[64 * 32];

  const int tid = threadIdx.x;
  const int lane = tid & 63, w = tid >> 6;
  const int wm = w >> 1, wn = w & 1;
  const int quad = lane >> 4, r16 = lane & 15;
  const int bm = blockIdx.y * 64, bn = blockIdx.x * 64;

  const int srow = tid >> 2, skseg = tid & 3;
  const ushort_t* Ag = A + (size_t)(bm + srow) * K + skseg * 8;
  const short* Bg = Bt + (size_t)(bn + srow) * K + skseg * 8;
  short* lA = As + w * 512;
  short* lB = Bs + w * 512;

  float4v acc[2][2];
#pragma unroll
  for (int m = 0; m < 2; ++m)
#pragma unroll
    for (int n = 0; n < 2; ++n) acc[m][n] = (float4v){0.f, 0.f, 0.f, 0.f};

  for (int k0 = 0; k0 < K; k0 += 32) {
    __syncthreads();
    glds16(Ag + k0, lA);
    glds16(Bg + k0, lB);
    __syncthreads();

    short8 af[2], bfr[2];
#pragma unroll
    for (int m = 0; m < 2; ++m)
      af[m] = *(const short8*)&As[(wm * 32 + m * 16 + r16) * 32 + quad * 8];
#pragma unroll
    for (int n = 0; n < 2; ++n)
      bfr[n] = *(const short8*)&Bs[(wn * 32 + n * 16 + r16) * 32 + quad * 8];
#pragma unroll
    for (int m = 0; m < 2; ++m)
#pragma unroll
      for (int n = 0; n < 2; ++n)
        acc[m][n] = __builtin_amdgcn_mfma_f32_16x16x32_bf16(af[m], bfr[n],
                                                            acc[m][n], 0, 0, 0);
  }

  const float pe_c = (float)(-9.210340371976184 / 512.0);
  const float sqrtd = 22.62741699796952f;

  float bias_n[2];
#pragma unroll
  for (int n = 0; n < 2; ++n) bias_n[n] = bias[bn + wn * 32 + n * 16 + r16];

#pragma unroll
  for (int m = 0; m < 2; ++m) {
#pragma unroll
    for (int n = 0; n < 2; ++n) {
      int col = bn + wn * 32 + n * 16 + r16;
#pragma unroll
      for (int reg = 0; reg < 4; ++reg) {
        int row = bm + wm * 32 + m * 16 + quad * 4 + reg;
        float v = acc[m][n][reg] + bias_n[n];
        if (RELU) v = fmaxf(v, 0.f);
        if (EPI == 2) {
          int pos = row & (SEQ - 1);
          float e = __expf((float)(col & ~1) * pe_c);
          float arg = (float)pos * e;
          v = v * sqrtd + ((col & 1) ? __cosf(arg) : __sinf(arg));
        }
        if (ADDC) v += bf2f(Cadd[(size_t)row * N + col]);
        if (OUTBF16) {
          ((ushort_t*)Cout)[(size_t)row * N + col] = f2bf(v);
        } else {
          ((float*)Cout)[(size_t)row * N + col] = v;
        }
      }
    }
  }
}

// ---------------------------------------------------------------------------
// All weights (3 layers + emb + dec): W[K][N] f32 -> Wt[N][K] bf16, 1 launch.
// ---------------------------------------------------------------------------
__global__ __launch_bounds__(256) void convert_all(
    const float* __restrict__ Wq, const float* __restrict__ Wk,
    const float* __restrict__ Wv, const float* __restrict__ Wo,
    const float* __restrict__ W1, const float* __restrict__ W2,
    const float* __restrict__ W_emb, const float* __restrict__ W_dec,
    short* __restrict__ wt) {
  __shared__ float t[32][33];
  int id = blockIdx.x;
  const float* src;
  short* dst;
  int K, N, tk, tn;
  if (id < 9216) {
    int lay = id / 3072, r = id % 3072;
    short* wl = wt + (size_t)lay * 3145728;
    const size_t wsz = 512 * 512;
    if (r < 1024) {
      int wi = r >> 8, tile = r & 255;
      const float* base = (wi == 0) ? Wq : (wi == 1) ? Wk : (wi == 2) ? Wv : Wo;
      src = base + lay * wsz;
      dst = wl + wi * 262144;
      K = 512; N = 512; tk = tile >> 4; tn = tile & 15;
    } else if (r < 2048) {
      int tile = r - 1024;
      src = W1 + (size_t)lay * 512 * 2048;
      dst = wl + 1048576;
      K = 512; N = 2048; tk = tile >> 6; tn = tile & 63;
    } else {
      int tile = r - 2048;
      src = W2 + (size_t)lay * 2048 * 512;
      dst = wl + 2097152;
      K = 2048; N = 512; tk = tile >> 4; tn = tile & 15;
    }
  } else {
    int r = id - 9216;
    if (r < 64) {
      src = W_emb; dst = wt + 9437184; K = 128; N = 512; tk = r >> 4; tn = r & 15;
    } else {
      r -= 64;
      src = W_dec; dst = wt + 9502720; K = 512; N = 64; tk = r >> 1; tn = r & 1;
    }
  }
  const int k0 = tk * 32, n0 = tn * 32;
  const int tx = threadIdx.x, ty = threadIdx.y;
#pragma unroll
  for (int i = 0; i < 4; ++i) {
    int r = ty + i * 8;
    t[r][tx] = src[(size_t)(k0 + r) * N + n0 + tx];
  }
  __syncthreads();
#pragma unroll
  for (int i = 0; i < 4; ++i) {
    int r = ty + i * 8;
    dst[(size_t)(n0 + r) * K + k0 + tx] = (short)f2bf(t[tx][r]);
  }
}

__global__ __launch_bounds__(256) void f32_to_bf16_kernel(
    const float* __restrict__ src, ushort_t* __restrict__ dst) {
  int i = blockIdx.x * blockDim.x + threadIdx.x;
  float4 v = ((const float4*)src)[i];
  ushort4 o;
  o.x = f2bf(v.x); o.y = f2bf(v.y); o.z = f2bf(v.z); o.w = f2bf(v.w);
  ((ushort4*)dst)[i] = o;
}

// ---------------------------------------------------------------------------
// Split-K reduce + residual + LayerNorm: hb = LN(pa + pb + hb) * g + b.
// ---------------------------------------------------------------------------
__global__ __launch_bounds__(256) void ln_red_kernel(
    const ushort_t* __restrict__ pa, const ushort_t* __restrict__ pb,
    const float* __restrict__ g, const float* __restrict__ bb,
    ushort_t* __restrict__ hb) {
  const int row = blockIdx.x * 4 + (threadIdx.x >> 6);
  const int lane = threadIdx.x & 63;
  const size_t base = (size_t)row * DMODEL + lane * 8;
  uint4 ra = *(const uint4*)(pa + base);
  uint4 rb = *(const uint4*)(pb + base);
  uint4 rh = *(const uint4*)(hb + base);
  unsigned aa[4] = {ra.x, ra.y, ra.z, ra.w};
  unsigned ab[4] = {rb.x, rb.y, rb.z, rb.w};
  unsigned ah[4] = {rh.x, rh.y, rh.z, rh.w};
  float v[8];
#pragma unroll
  for (int k = 0; k < 4; ++k) {
    v[2 * k] = bf2f((ushort_t)(aa[k] & 0xffff)) +
               bf2f((ushort_t)(ab[k] & 0xffff)) +
               bf2f((ushort_t)(ah[k] & 0xffff));
    v[2 * k + 1] = bf2f((ushort_t)(aa[k] >> 16)) +
                   bf2f((ushort_t)(ab[k] >> 16)) +
                   bf2f((ushort_t)(ah[k] >> 16));
  }
  float sum = 0.f, sq = 0.f;
#pragma unroll
  for (int k = 0; k < 8; ++k) { sum += v[k]; sq += v[k] * v[k]; }
#pragma unroll
  for (int off = 32; off; off >>= 1) {
    sum += __shfl_xor(sum, off);
    sq += __shfl_xor(sq, off);
  }
  float mean = sum * (1.f / 512.f);
  float var = fmaxf(sq * (1.f / 512.f) - mean * mean, 0.f);
  float rstd = 1.f / sqrtf(var + 1e-5f);
  float4 g0 = *(const float4*)(g + lane * 8);
  float4 g1 = *(const float4*)(g + lane * 8 + 4);
  float4 c0 = *(const float4*)(bb + lane * 8);
  float4 c1 = *(const float4*)(bb + lane * 8 + 4);
  float gg[8] = {g0.x, g0.y, g0.z, g0.w, g1.x, g1.y, g1.z, g1.w};
  float cc[8] = {c0.x, c0.y, c0.z, c0.w, c1.x, c1.y, c1.z, c1.w};
  uint4 out;
  unsigned* op = (unsigned*)&out;
#pragma unroll
  for (int k = 0; k < 4; ++k) {
    float y0 = (v[2 * k] - mean) * rstd * gg[2 * k] + cc[2 * k];
    float y1 = (v[2 * k + 1] - mean) * rstd * gg[2 * k + 1] + cc[2 * k + 1];
    op[k] = (unsigned)f2bf(y0) | ((unsigned)f2bf(y1) << 16);
  }
  *(uint4*)(hb + base) = out;
}

// ---------------------------------------------------------------------------
// ProbSparse attention v9:
// - XCD-affinity swizzle: all 64 q-tile blocks of one (b,h) land on one XCD
//   (id%8 round-robin heuristic) -> K/V fetched once per XCD L2, PV gathers
//   become L2 hits.
// - Phase 2 register-caches all scores: 8 ds_read_b32/query (packed fp16
//   pairs, lane owns j = 2*lane+(i&1)+128*(i>>1)), no LDS re-read passes.
// - Compaction stores fp16 SCORE; exp deferred to the final keep set.
// ---------------------------------------------------------------------------
#define SST 1048

__global__ __launch_bounds__(512, 8) void attn_kernel(
    const ushort_t* __restrict__ Qb, const ushort_t* __restrict__ Kb,
    const ushort_t* __restrict__ Vb, ushort_t* __restrict__ Ob) {
  __shared__ _Float16 s16[16 * SST];
  __shared__ unsigned plist[16][64];

  const int tid = threadIdx.x;
  // XCD swizzle: grid (64, 8, 4) -> each XCD owns 4 (b,h) pairs x 64 q-tiles
  const int id = blockIdx.x + 64 * (blockIdx.y + 8 * blockIdx.z);
  const int xcd = id & 7;
  const int loc = id >> 3;
  const int bh = xcd * 4 + (loc & 3);
  const int q0 = (loc >> 2) * 16;
  const int b = bh >> 3;
  const int h = bh & 7;

  const int w = tid >> 6;
  const int lane = tid & 63;
  const int quad = lane >> 4, r16 = lane & 15;

  // ---- Phase 1: MFMA scores (16 queries x 128 keys per wave) ----
  {
    const int j0 = w * 128;
    const ushort_t* qrow =
        Qb + (size_t)(b * SEQ + q0 + r16) * DMODEL + h * DK + quad * 8;
    short8 aq0 = *(const short8*)qrow;
    short8 aq1 = *(const short8*)(qrow + 32);

#pragma unroll
    for (int nt = 0; nt < 8; ++nt) {
      const ushort_t* krow =
          Kb + (size_t)(b * SEQ + j0 + nt * 16 + r16) * DMODEL + h * DK +
          quad * 8;
      short8 bk0 = *(const short8*)krow;
      short8 bk1 = *(const short8*)(krow + 32);
      float4v a = (float4v){0.f, 0.f, 0.f, 0.f};
      a = __builtin_amdgcn_mfma_f32_16x16x32_bf16(aq0, bk0, a, 0, 0, 0);
      a = __builtin_amdgcn_mfma_f32_16x16x32_bf16(aq1, bk1, a, 0, 0, 0);
#pragma unroll
      for (int reg = 0; reg < 4; ++reg)
        s16[(quad * 4 + reg) * SST + j0 + nt * 16 + r16] =
            (_Float16)(a[reg] * 0.125f);
    }
  }
  __syncthreads();

  // ---- Phase 2: two queries per wave, scores register-cached ----
  {
    const int qa = w, qb2 = w + 8;
    const _Float16* sa = &s16[qa * SST];
    const _Float16* sb = &s16[qb2 * SST];
    const unsigned* sa32 = (const unsigned*)sa;
    const unsigned* sb32 = (const unsigned*)sb;

    // load all scores once: 8 packed u32 per query
    unsigned pk_a[8], pk_b[8];
#pragma unroll
    for (int i = 0; i < 8; ++i) {
      pk_a[i] = sa32[lane + 64 * i];
      pk_b[i] = sb32[lane + 64 * i];
    }

    // lane maxima from registers
    float la = -1e30f, lb = -1e30f;
#pragma unroll
    for (int i = 0; i < 8; ++i) {
      la = fmaxf(la, fmaxf(lo16(pk_a[i]), hi16(pk_a[i])));
      lb = fmaxf(lb, fmaxf(lo16(pk_b[i]), hi16(pk_b[i])));
    }

    float sva = la, svb = lb;
    bitonic64x2(sva, svb, lane);
    const float mxa = __shfl(sva, 0), mxb = __shfl(svb, 0);
    const float fTa = __shfl(sva, 33), fTb = __shfl(svb, 33);

    // optimistic compaction at fT; store (j<<16 | fp16 score)
    int ca = 0, cb = 0;
#pragma unroll
    for (int i = 0; i < 16; ++i) {
      float va = (i & 1) ? hi16(pk_a[i >> 1]) : lo16(pk_a[i >> 1]);
      float vb = (i & 1) ? hi16(pk_b[i >> 1]) : lo16(pk_b[i >> 1]);
      int j = 2 * lane + (i & 1) + 128 * (i >> 1);
      bool ka = va >= fTa, kb = vb >= fTb;
      unsigned long long ma = __ballot(ka);
      unsigned long long mb = __ballot(kb);
      if (ka) {
        int p = ca + mbcnt64(ma);
        if (p < 64) plist[qa][p] = ((unsigned)j << 16) | h2u(va);
      }
      if (kb) {
        int p = cb + mbcnt64(mb);
        if (p < 64) plist[qb2][p] = ((unsigned)j << 16) | h2u(vb);
      }
      ca += (int)__popcll(ma);
      cb += (int)__popcll(mb);
    }

    // rare fallback: >64 candidates -> bisection to tighter threshold
    if (__builtin_expect(ca > 64, 0)) {
      unsigned ans = 0u;
      int cge = ca;
      bool ex = false;
      for (int bit = 31; bit >= 0 && cge > 64 && !ex; --bit) {
        unsigned cand = ans | (1u << bit);
        float fc = keyinv(cand);
        int c = 0;
#pragma unroll
        for (int i = 0; i < 16; ++i)
          c += (int)__popcll(__ballot((float)sa[lane + 64 * i] >= fc));
        if (c >= U_TOP) { ans = cand; cge = c; ex = (c == U_TOP); }
      }
      float fa2 = keyinv(ans);
      int cc = 0;
#pragma unroll
      for (int i = 0; i < 16; ++i) {
        float va = (float)sa[lane + 64 * i];
        bool ka = va >= fa2;
        unsigned long long ma = __ballot(ka);
        if (ka) {
          int p = cc + mbcnt64(ma);
          if (p < 64)
            plist[qa][p] = ((unsigned)(lane + 64 * i) << 16) | h2u(va);
        }
        cc += (int)__popcll(ma);
      }
      ca = cc;
    }
    if (__builtin_expect(cb > 64, 0)) {
      unsigned ans = 0u;
      int cge = cb;
      bool ex = false;
      for (int bit = 31; bit >= 0 && cge > 64 && !ex; --bit) {
        unsigned cand = ans | (1u << bit);
        float fc = keyinv(cand);
        int c = 0;
#pragma unroll
        for (int i = 0; i < 16; ++i)
          c += (int)__popcll(__ballot((float)sb[lane + 64 * i] >= fc));
        if (c >= U_TOP) { ans = cand; cge = c; ex = (c == U_TOP); }
      }
      float fb2 = keyinv(ans);
      int cc = 0;
#pragma unroll
      for (int i = 0; i < 16; ++i) {
        float vb = (float)sb[lane + 64 * i];
        bool kb = vb >= fb2;
        unsigned long long mb = __ballot(kb);
        if (kb) {
          int p = cc + mbcnt64(mb);
          if (p < 64)
            plist[qb2][p] = ((unsigned)(lane + 64 * i) << 16) | h2u(vb);
        }
        cc += (int)__popcll(mb);
      }
      cb = cc;
    }
    ca = ca > 64 ? 64 : ca;
    cb = cb > 64 ? 64 : cb;

    // one candidate per lane; scores in low bits
    unsigned pua = (lane < ca) ? plist[qa][lane] : 0u;
    unsigned pub = (lane < cb) ? plist[qb2][lane] : 0u;
    float cfa = (lane < ca) ? u2h((unsigned short)(pua & 0xffffu)) : -3.4e38f;
    float cfb = (lane < cb) ? u2h((unsigned short)(pub & 0xffffu)) : -3.4e38f;

    // sort2 over candidate scores -> exact 34th-largest
    float s2a = cfa, s2b = cfb;
    bitonic64x2(s2a, s2b, lane);
    const float tha = __shfl(s2a, 33), thb = __shfl(s2b, 33);

    // final keep set; exp only now
    bool keepa = cfa >= tha, keepb = cfb >= thb;
    unsigned long long kma = __ballot(keepa);
    unsigned long long kmb = __ballot(keepb);
    int na = (int)__popcll(kma), nb = (int)__popcll(kmb);
    float ea = keepa ? __expf(cfa - mxa) : 0.f;
    float eb = keepb ? __expf(cfb - mxb) : 0.f;
    float za = ea, zb = eb;
#pragma unroll
    for (int off = 32; off; off >>= 1) {
      za += __shfl_xor(za, off);
      zb += __shfl_xor(zb, off);
    }
    int posa = mbcnt64(kma), posb = mbcnt64(kmb);
    if (keepa) plist[qa][posa] = (pua & 0xffff0000u) | h2u(ea);
    if (keepb) plist[qb2][posb] = (pub & 0xffff0000u) | h2u(eb);

    // sparse PV: two interleaved gather streams
    const ushort_t* vbase = Vb + (size_t)b * SEQ * DMODEL + h * DK;
    float oa = 0.f, ob = 0.f;
    int nmax = na > nb ? na : nb;
    for (int i = 0; i < nmax; i += 2) {
      unsigned ua0 = (i < na) ? plist[qa][i] : 0u;
      unsigned ua1 = (i + 1 < na) ? plist[qa][i + 1] : 0u;
      unsigned ub0 = (i < nb) ? plist[qb2][i] : 0u;
      unsigned ub1 = (i + 1 < nb) ? plist[qb2][i + 1] : 0u;
      float pa0 = bf2f(vbase[(size_t)(ua0 >> 16) * DMODEL + lane]);
      float pa1 = bf2f(vbase[(size_t)(ua1 >> 16) * DMODEL + lane]);
      float pb0 = bf2f(vbase[(size_t)(ub0 >> 16) * DMODEL + lane]);
      float pb1 = bf2f(vbase[(size_t)(ub1 >> 16) * DMODEL + lane]);
      oa += u2h((unsigned short)(ua0 & 0xffffu)) * pa0 +
            u2h((unsigned short)(ua1 & 0xffffu)) * pa1;
      ob += u2h((unsigned short)(ub0 & 0xffffu)) * pb0 +
            u2h((unsigned short)(ub1 & 0xffffu)) * pb1;
    }
    oa /= za;
    ob /= zb;
    Ob[(size_t)(b * SEQ + q0 + qa) * DMODEL + h * DK + lane] = f2bf(oa);
    Ob[(size_t)(b * SEQ + q0 + qb2) * DMODEL + h * DK + lane] = f2bf(ob);
  }
}

// ---------------------------------------------------------------------------
// Orchestration.  ws layout (MiB): ffh/qkv [0,16) (Wo partials reuse [0,8)
// after attn) | ao [16,20) (xb pre-loop; FFN2 partials reuse [16,24)) |
// [20,24) FFN2 partial 1 | hb [24,28) | wt [28, 46.2).
// ---------------------------------------------------------------------------
extern "C" void kernel_launch(void* const* d_in, const int* in_sizes, int n_in,
                              void* d_out, int out_size, void* d_ws,
                              size_t ws_size, hipStream_t stream) {
  const float* x = (const float*)d_in[0];
  const float* W_emb = (const float*)d_in[1];
  const float* b_emb = (const float*)d_in[2];
  const float* Wq = (const float*)d_in[3];
  const float* bq = (const float*)d_in[4];
  const float* Wk = (const float*)d_in[5];
  const float* bk = (const float*)d_in[6];
  const float* Wv = (const float*)d_in[7];
  const float* bv = (const float*)d_in[8];
  const float* Wo = (const float*)d_in[9];
  const float* bo = (const float*)d_in[10];
  const float* ln1_g = (const float*)d_in[11];
  const float* ln1_b = (const float*)d_in[12];
  const float* W1 = (const float*)d_in[13];
  const float* b1 = (const float*)d_in[14];
  const float* W2 = (const float*)d_in[15];
  const float* b2 = (const float*)d_in[16];
  const float* ln2_g = (const float*)d_in[17];
  const float* ln2_b = (const float*)d_in[18];
  const float* W_dec = (const float*)d_in[19];
  const float* b_dec = (const float*)d_in[20];

  char* wsb = (char*)d_ws;
  ushort_t* qkv = (ushort_t*)wsb;
  ushort_t* ffh = (ushort_t*)wsb;
  ushort_t* wop = (ushort_t*)wsb;  // Wo partials [0,8M)
  ushort_t* ao = (ushort_t*)(wsb + ((size_t)16 << 20));
  ushort_t* xb = (ushort_t*)(wsb + ((size_t)16 << 20));
  ushort_t* ffp = (ushort_t*)(wsb + ((size_t)16 << 20));  // FFN2 partials
  ushort_t* hb = (ushort_t*)(wsb + ((size_t)24 << 20));
  short* wt = (short*)(wsb + ((size_t)28 << 20));
  short* wembT = wt + 9437184;
  short* wdecT = wt + 9502720;

  f32_to_bf16_kernel<<<dim3(512), 256, 0, stream>>>(x, xb);
  convert_all<<<dim3(9312), dim3(32, 8), 0, stream>>>(Wq, Wk, Wv, Wo, W1, W2,
                                                      W_emb, W_dec, wt);
  // embed: hb = bf16((xb @ W_emb + b_emb)*sqrt(512) + PE)
  gemm64<0, 1, 2, 0><<<dim3(8, 64), 256, 0, stream>>>(
      xb, wembT, b_emb, (void*)hb, nullptr, 128, 512);

  for (int i = 0; i < 3; ++i) {
    short* wtL = wt + (size_t)i * 3145728;

    // QKV: one N=1536 GEMM on the 128x128 tile, z-split epilogue
    gemm128<0, 1><<<dim3(12, 32), 256, 0, stream>>>(
        hb, wtL, bq + i * DMODEL, bk + i * DMODEL, bv + i * DMODEL, qkv, 512,
        512, 2097152);

    attn_kernel<<<dim3(SEQ / 16, NHEAD, BATCH), dim3(512), 0, stream>>>(
        qkv, qkv + 2097152, qkv + 4194304, ao);

    // Wo split-K (K=512 -> 2x256): partials over dead qkv region
    gemm128sk<<<dim3(4, 32, 2), 256, 0, stream>>>(
        ao, wtL + 786432, bo + i * DMODEL, wop, 512, 256);
    ln_red_kernel<<<dim3(ROWS / 4), 256, 0, stream>>>(
        wop, wop + 2097152, ln1_g + i * DMODEL, ln1_b + i * DMODEL, hb);

    // FFN1 on the 128x128 tile (N=2048)
    gemm128<1, 0><<<dim3(16, 32), 256, 0, stream>>>(
        hb, wtL + 1048576, b1 + i * DFF, nullptr, nullptr, ffh, 512, 2048, 0);
    // FFN2 split-K (K=2048 -> 2x1024): partials over dead ao region
    gemm128sk<<<dim3(4, 32, 2), 256, 0, stream>>>(
        ffh, wtL + 2097152, b2 + i * DMODEL, ffp, 2048, 1024);
    ln_red_kernel<<<dim3(ROWS / 4), 256, 0, stream>>>(
        ffp, ffp + 2097152, ln2_g + i * DMODEL, ln2_b + i * DMODEL, hb);
  }

  gemm64<0, 0, 0, 0><<<dim3(1, 64), 256, 0, stream>>>(
      hb, wdecT, b_dec, d_out, nullptr, 512, 64);
}